// Round 1
// 4989.190 us; speedup vs baseline: 1.1695x; 1.1695x over previous
//
#include <hip/hip_runtime.h>

#define N_CLOUDS 16
#define PTS      16384
#define M        4096
#define THREADS  512
#define NWAVES   (THREADS / 64)    // 8 waves
#define PPT      32                // consecutive (sorted-order) points per thread

typedef float v2f __attribute__((ext_vector_type(2)));
typedef unsigned long long u64;
typedef unsigned int u32;
typedef unsigned short u16;

// Round-6: exact wave-level pruning (QuickFPS-style, bit-exact).
//  - sort_kernel (one-time, ~0.1ms): per cloud, order points by quantized x
//    (bitonic in 64KB LDS), each 32-chunk re-sorted ascending by ORIGINAL
//    index (preserves first-occurrence argmax ties exactly), writes reordered
//    coords + slot-major u16 orig-map to workspace.
//  - fps_kernel: per wave, cache the post-reduce wave key (max DD, in SGPRs).
//    Per iteration, skip the whole 32-pt update iff
//    dist_x(q, wave_x_slab)^2 * 0.9999 > cached max DD  -- every min(DD,nd)
//    is then a provable no-op (fp32 error bound ~5e-7 << 1e-4 margin), so
//    skipping is bit-exact. Winner's wave always active (lb=0).
//  - key low bits = ~orig index via LDS map read (slot-major, conflict-free),
//    so tie-break/output semantics are IDENTICAL to the round-5 kernel.
//  - fallback (ws too small): SORTED=false == round-5 kernel behavior.

#define PAIRS_X(X) X(0) X(1) X(2) X(3) X(4) X(5) X(6) X(7) \
                   X(8) X(9) X(10) X(11) X(12) X(13) X(14) X(15)
#define F24_X(X) X(0) X(1) X(2) X(3) X(4) X(5) X(6) X(7) X(8) X(9) X(10) X(11) \
                 X(12) X(13) X(14) X(15) X(16) X(17) X(18) X(19) X(20) X(21) X(22) X(23)
#define QUADS_X(X) X(0,1,0,1,2)     X(2,3,3,4,5)     X(4,5,6,7,8)     X(6,7,9,10,11) \
                   X(8,9,12,13,14)  X(10,11,15,16,17) X(12,13,18,19,20) X(14,15,21,22,23)

// u64 max-combine with DPP-shifted copy (old=0 is identity: keys >= 0)
#define DPP_MAX_STEP(key, CTRL) { \
        const u32 lo_  = (u32)(key); \
        const u32 hi_  = (u32)((key) >> 32); \
        const u32 lo2_ = (u32)__builtin_amdgcn_update_dpp(0, (int)lo_, (CTRL), 0xf, 0xf, false); \
        const u32 hi2_ = (u32)__builtin_amdgcn_update_dpp(0, (int)hi_, (CTRL), 0xf, 0xf, false); \
        const u64 ok_  = ((u64)hi2_ << 32) | lo2_; \
        (key) = (ok_ > (key)) ? ok_ : (key); \
    }

// float min/max wave-reduce step; old = own value (identity for masked lanes)
#define DPP_FMIN_STEP(v, CTRL) { \
        const int t_ = __builtin_amdgcn_update_dpp(__float_as_int(v), __float_as_int(v), (CTRL), 0xf, 0xf, false); \
        (v) = fminf((v), __int_as_float(t_)); \
    }
#define DPP_FMAX_STEP(v, CTRL) { \
        const int t_ = __builtin_amdgcn_update_dpp(__float_as_int(v), __float_as_int(v), (CTRL), 0xf, 0xf, false); \
        (v) = fmaxf((v), __int_as_float(t_)); \
    }
#define DPP_RED6(MACRO, v) \
        MACRO(v, 0x111) MACRO(v, 0x112) MACRO(v, 0x114) MACRO(v, 0x118) \
        MACRO(v, 0x142) MACRO(v, 0x143)

// ---------------------------------------------------------------------------
// One-time spatial ordering kernel: one block per cloud.
// keys: (quantized_x << 14) | orig_idx  -> bitonic sort -> per-32-chunk
// re-sort by orig -> emit reordered coords + slot-major u16 map.
// Correctness of fps does NOT depend on sort quality, only on the map being a
// permutation (guaranteed: keys unique) -- sort quality only affects pruning.
// ---------------------------------------------------------------------------
__global__ __launch_bounds__(THREADS)
void sort_kernel(const float* __restrict__ pos, float* __restrict__ pos_s,
                 u16* __restrict__ mapT)
{
    __shared__ u32 keys[PTS];          // 64 KiB
    const int cloud = blockIdx.x;
    const int tid   = threadIdx.x;
    const int ln    = tid & 63;
    const size_t b3 = (size_t)cloud * PTS * 3;

    // ---- x range of this cloud ----
    float mn = 1e30f, mx = -1e30f;
    for (int s = 0; s < PTS / THREADS; ++s) {
        const float x = pos[b3 + (size_t)(tid + s * THREADS) * 3];
        mn = fminf(mn, x);
        mx = fmaxf(mx, x);
    }
    DPP_RED6(DPP_FMIN_STEP, mn)
    DPP_RED6(DPP_FMAX_STEP, mx)
    float* red = (float*)keys;         // reuse LDS before keys are written
    if (ln == 63) { red[tid >> 6] = mn; red[NWAVES + (tid >> 6)] = mx; }
    __syncthreads();
    float xmin = red[0], xmax = red[NWAVES];
    for (int w = 1; w < NWAVES; ++w) {
        xmin = fminf(xmin, red[w]);
        xmax = fmaxf(xmax, red[NWAVES + w]);
    }
    __syncthreads();

    // ---- build keys: 18-bit quantized x | 14-bit orig index ----
    const float scale = 262143.0f / fmaxf(xmax - xmin, 1e-30f);
    for (int s = 0; s < PTS / THREADS; ++s) {
        const int i = tid + s * THREADS;
        const float x = pos[b3 + (size_t)i * 3];
        const u32 q = (u32)fminf(fmaxf((x - xmin) * scale, 0.0f), 262143.0f);
        keys[i] = (q << 14) | (u32)i;
    }

    // ---- bitonic sort 16384 u32 keys in LDS ----
    for (u32 k = 2; k <= (u32)PTS; k <<= 1) {
        for (u32 j = k >> 1; j; j >>= 1) {
            __syncthreads();
            for (int s = 0; s < PTS / THREADS; ++s) {
                const u32 i = (u32)(tid + s * THREADS);
                const u32 p = i ^ j;
                if (p > i) {
                    const u32 a = keys[i], b = keys[p];
                    if (((i & k) == 0) == (a > b)) { keys[i] = b; keys[p] = a; }
                }
            }
        }
    }
    __syncthreads();

    // ---- within each 32-chunk, re-sort ascending by ORIGINAL index so the
    //      fps thread's slot order == orig order (exact tie semantics) ----
    {
        u32 loc[PPT];
        const int cb = tid * PPT;
        for (int s = 0; s < PPT; ++s) loc[s] = keys[cb + s] & (u32)(PTS - 1);
        for (int a = 1; a < PPT; ++a) {
            const u32 v = loc[a];
            int b = a;
            while (b > 0 && loc[b - 1] > v) { loc[b] = loc[b - 1]; --b; }
            loc[b] = v;
        }
        for (int s = 0; s < PPT; ++s) keys[cb + s] = loc[s];
    }
    __syncthreads();

    // ---- emit reordered coords (bit-copies) + slot-major map ----
    for (int s = 0; s < PTS / THREADS; ++s) {
        const int i = tid + s * THREADS;       // sorted position
        const u32 orig = keys[i];
        mapT[(size_t)cloud * PTS + (size_t)(i & (PPT - 1)) * THREADS + (i >> 5)] = (u16)orig;
        const size_t so = b3 + (size_t)i * 3;
        const size_t oo = b3 + (size_t)orig * 3;
        pos_s[so + 0] = pos[oo + 0];
        pos_s[so + 1] = pos[oo + 1];
        pos_s[so + 2] = pos[oo + 2];
    }
}

// ---------------------------------------------------------------------------
// Main FPS kernel (one block per cloud). SORTED=false == round-5 behavior.
// ---------------------------------------------------------------------------
template<bool SORTED>
__global__ __launch_bounds__(THREADS)
__attribute__((amdgpu_waves_per_eu(2, 2)))
void fps_kernel(const float* __restrict__ pos,      // original (winner fetch, q0)
                const float* __restrict__ psrc,     // sorted coords (or == pos)
                const u16* __restrict__ mapT,       // slot-major orig map (or null)
                int* __restrict__ out)
{
#pragma clang fp contract(off)
    const int cloud = blockIdx.x;
    const int tid   = threadIdx.x;
    const int base  = cloud * PTS;
    const int wave  = tid >> 6;
    const int lane  = tid & 63;

    __shared__ u64 skey[2][NWAVES];
    __shared__ __attribute__((aligned(16))) u16 mlds[PTS];   // [slot][thread]

    if constexpr (SORTED) {
        // stage orig-index map into LDS (coalesced uint4 copy)
        const uint4* src = (const uint4*)(mapT + (size_t)cloud * PTS);
        uint4* dst = (uint4*)mlds;
#pragma unroll
        for (int s = 0; s < PTS * 2 / 16 / THREADS; ++s)     // 4 iters
            dst[s * THREADS + tid] = src[s * THREADS + tid];
        __syncthreads();
    }

    // ---- query = point 0 of cloud (ORIGINAL order) ----
    const float q0x = pos[(size_t)base * 3 + 0];
    const float q0y = pos[(size_t)base * 3 + 1];
    const float q0z = pos[(size_t)base * 3 + 2];
    v2f qx2 = {q0x, q0x}, qy2 = {q0y, q0y}, qz2 = {q0z, q0z};

    // ---- one-time vectorized load: 32 consecutive pts = 24 float4 ----
    const float4* pos4 = (const float4*)psrc;
    const int fo = cloud * (PTS * 3 / 4) + tid * (PPT * 3 / 4);
#define LOADF(n) const float4 f##n = pos4[fo + (n)];
    F24_X(LOADF)
#undef LOADF

#define DECL(j) v2f XX##j, YY##j, ZZ##j, DD##j;
    PAIRS_X(DECL)
#undef DECL
#define REPACK(j0, j1, a, b, c) \
        XX##j0 = (v2f){f##a.x, f##a.w}; \
        YY##j0 = (v2f){f##a.y, f##b.x}; \
        ZZ##j0 = (v2f){f##a.z, f##b.y}; \
        XX##j1 = (v2f){f##b.z, f##c.y}; \
        YY##j1 = (v2f){f##b.w, f##c.z}; \
        ZZ##j1 = (v2f){f##c.x, f##c.w};
    QUADS_X(REPACK)
#undef REPACK

#define PIN8(a,b,c,d,e,g,h,k) asm volatile("" : "+v"(a),"+v"(b),"+v"(c),"+v"(d),"+v"(e),"+v"(g),"+v"(h),"+v"(k));
    PIN8(XX0, XX1, XX2, XX3, XX4, XX5, XX6, XX7)
    PIN8(XX8, XX9, XX10, XX11, XX12, XX13, XX14, XX15)
    PIN8(YY0, YY1, YY2, YY3, YY4, YY5, YY6, YY7)
    PIN8(YY8, YY9, YY10, YY11, YY12, YY13, YY14, YY15)
    PIN8(ZZ0, ZZ1, ZZ2, ZZ3, ZZ4, ZZ5, ZZ6, ZZ7)
    PIN8(ZZ8, ZZ9, ZZ10, ZZ11, ZZ12, ZZ13, ZZ14, ZZ15)
#undef PIN8

    // ---- wave x-slab bounds (TRUE min/max of this wave's points) ----
    float wxlo, wxhi;
    {
        float mn = fminf(XX0.x, XX0.y);
        float mx = fmaxf(XX0.x, XX0.y);
#define MINMAX(j) { mn = fminf(mn, fminf(XX##j.x, XX##j.y)); \
                    mx = fmaxf(mx, fmaxf(XX##j.x, XX##j.y)); }
        MINMAX(1) MINMAX(2) MINMAX(3) MINMAX(4) MINMAX(5) MINMAX(6) MINMAX(7)
        MINMAX(8) MINMAX(9) MINMAX(10) MINMAX(11) MINMAX(12) MINMAX(13) MINMAX(14) MINMAX(15)
#undef MINMAX
        DPP_RED6(DPP_FMIN_STEP, mn)
        DPP_RED6(DPP_FMAX_STEP, mx)
        wxlo = __int_as_float(__builtin_amdgcn_readlane(__float_as_int(mn), 63));
        wxhi = __int_as_float(__builtin_amdgcn_readlane(__float_as_int(mx), 63));
    }

    // ---- init dists to point 0 + lane-local argmax ----
    float bd = -1.0f;
    int   bk = 0;
#define INITP(j) { \
        v2f dx = XX##j - qx2; \
        v2f dy = YY##j - qy2; \
        v2f dz = ZZ##j - qz2; \
        v2f nd = (dx * dx + dy * dy) + dz * dz; \
        DD##j = nd; \
        if (nd.x > bd) { bd = nd.x; bk = 2*(j); } \
        if (nd.y > bd) { bd = nd.y; bk = 2*(j) + 1; } \
    }
    PAIRS_X(INITP)
#undef INITP

    if (tid == 0) out[cloud * M] = base;   // first sample = point 0

    // ---- initial wave key (same as the loop's active path) ----
    u32 c_hi, c_lo;                        // cached wave key (uniform, SGPRs)
    {
        int bi;
        if constexpr (SORTED) bi = (int)mlds[(bk << 9) + tid];
        else                  bi = tid * PPT + bk;
        u64 key = ((u64)__float_as_uint(bd) << 32) | (u32)(~bi);
        DPP_MAX_STEP(key, 0x111)
        DPP_MAX_STEP(key, 0x112)
        DPP_MAX_STEP(key, 0x114)
        DPP_MAX_STEP(key, 0x118)
        DPP_MAX_STEP(key, 0x142)
        DPP_MAX_STEP(key, 0x143)
        c_hi = (u32)__builtin_amdgcn_readlane((int)(u32)(key >> 32), 63);
        c_lo = (u32)__builtin_amdgcn_readlane((int)(u32)key, 63);
    }

    for (int i = 1; i < M; ++i) {
        // ---- publish this wave's current best key (cached; always valid) ----
        if (lane == 0) skey[i & 1][wave] = ((u64)c_hi << 32) | c_lo;
        __syncthreads();

        // ---- cross-wave: lanes hold the 8 wave keys, 3 DPP steps, lane 7 ----
        u64 key2 = skey[i & 1][lane & 7];
        DPP_MAX_STEP(key2, 0x111)
        DPP_MAX_STEP(key2, 0x112)
        DPP_MAX_STEP(key2, 0x114)
        const u32 wlo = (u32)__builtin_amdgcn_readlane((int)(u32)key2, 7);
        const int wi  = (int)(~wlo);            // winner ORIGINAL local index

        if (tid == 0) out[cloud * M + i] = base + wi;

        // ---- fetch winner coords from ORIGINAL array (uniform -> s_load) ----
        const float* qp = pos + (size_t)(base + wi) * 3;
        const float qx = qp[0], qy = qp[1], qz = qp[2];

        // ---- wave-level exact prune: skip iff dist_x(q, slab)^2 provably
        //      exceeds this wave's max min-dist (cached key hi) ----
        const float dlo  = wxlo - qx;
        const float dhi  = qx - wxhi;
        const float dgap = fmaxf(fmaxf(dlo, dhi), 0.0f);
        const float lb   = (dgap * dgap) * 0.9999f;   // margin >> fp32 error
        if (!(lb > __uint_as_float(c_hi))) {
            // ---- active: fused distance update + lane-local argmax ----
            qx2 = (v2f){qx, qx}; qy2 = (v2f){qy, qy}; qz2 = (v2f){qz, qz};
            bd = -1.0f; bk = 0;
#define UPD(j) { \
        v2f dx = XX##j - qx2; \
        v2f dy = YY##j - qy2; \
        v2f dz = ZZ##j - qz2; \
        v2f nd = (dx * dx + dy * dy) + dz * dz; \
        DD##j.x = fminf(DD##j.x, nd.x); \
        DD##j.y = fminf(DD##j.y, nd.y); \
        if (DD##j.x > bd) { bd = DD##j.x; bk = 2*(j); } \
        if (DD##j.y > bd) { bd = DD##j.y; bk = 2*(j) + 1; } \
    }
            PAIRS_X(UPD)
#undef UPD
            int bi;
            if constexpr (SORTED) bi = (int)mlds[(bk << 9) + tid];
            else                  bi = tid * PPT + bk;
            u64 key = ((u64)__float_as_uint(bd) << 32) | (u32)(~bi);
            DPP_MAX_STEP(key, 0x111)
            DPP_MAX_STEP(key, 0x112)
            DPP_MAX_STEP(key, 0x114)
            DPP_MAX_STEP(key, 0x118)
            DPP_MAX_STEP(key, 0x142)
            DPP_MAX_STEP(key, 0x143)
            c_hi = (u32)__builtin_amdgcn_readlane((int)(u32)(key >> 32), 63);
            c_lo = (u32)__builtin_amdgcn_readlane((int)(u32)key, 63);
        }
        // skipped: DD/bd/bk/c_* unchanged -- provably identical to full update
    }
}

extern "C" void kernel_launch(void* const* d_in, const int* in_sizes, int n_in,
                              void* d_out, int out_size, void* d_ws, size_t ws_size,
                              hipStream_t stream) {
    const float* pos = (const float*)d_in[0];
    int* out = (int*)d_out;

    const size_t pos_s_bytes = (size_t)N_CLOUDS * PTS * 3 * sizeof(float);   // 3 MiB
    const size_t map_bytes   = (size_t)N_CLOUDS * PTS * sizeof(u16);         // 0.5 MiB
    if (d_ws && ws_size >= pos_s_bytes + map_bytes) {
        float* pos_s = (float*)d_ws;
        u16*   mapT  = (u16*)((char*)d_ws + pos_s_bytes);
        sort_kernel<<<N_CLOUDS, THREADS, 0, stream>>>(pos, pos_s, mapT);
        fps_kernel<true><<<N_CLOUDS, THREADS, 0, stream>>>(pos, pos_s, mapT, out);
    } else {
        fps_kernel<false><<<N_CLOUDS, THREADS, 0, stream>>>(pos, pos, nullptr, out);
    }
}

// Round 2
// 4050.649 us; speedup vs baseline: 1.4405x; 1.2317x over previous
//
#include <hip/hip_runtime.h>

#define N_CLOUDS 16
#define PTS      16384
#define M        4096
#define FPS_THREADS  1024
#define NWAVES   (FPS_THREADS / 64)   // 16 waves
#define PPT      16                   // consecutive (sorted-order) points per thread
#define SORT_THREADS 512

typedef float v2f __attribute__((ext_vector_type(2)));
typedef unsigned long long u64;
typedef unsigned int u32;
typedef unsigned short u16;

// Round-7: finer pruning granularity + shorter active updates.
//  - fps kernel now 1024 threads = 16 waves, PPT=16: wave x-slabs halve
//    (more waves pass the exact slab prune), and an active wave's update
//    halves (~150 VALU). 4 waves/SIMD improves latency hiding.
//  - sort_kernel unchanged except: per-16-chunk orig re-sort (exact tie
//    semantics preserved: each fps thread's slots ascend in ORIGINAL index)
//    and slot-major map layout [16][1024].
//  - everything exactness-critical is identical to round-6: u64 key =
//    (dist_bits<<32)|~orig, DPP wave reduce, cached per-wave keys, prune
//    skip only when dist_x(q,slab)^2*0.9999 > wave max DD (provable no-op).

#define PAIRS8_X(X) X(0) X(1) X(2) X(3) X(4) X(5) X(6) X(7)

// u64 max-combine with DPP-shifted copy (old=0 is identity: keys >= 0)
#define DPP_MAX_STEP(key, CTRL) { \
        const u32 lo_  = (u32)(key); \
        const u32 hi_  = (u32)((key) >> 32); \
        const u32 lo2_ = (u32)__builtin_amdgcn_update_dpp(0, (int)lo_, (CTRL), 0xf, 0xf, false); \
        const u32 hi2_ = (u32)__builtin_amdgcn_update_dpp(0, (int)hi_, (CTRL), 0xf, 0xf, false); \
        const u64 ok_  = ((u64)hi2_ << 32) | lo2_; \
        (key) = (ok_ > (key)) ? ok_ : (key); \
    }

// float min/max wave-reduce step; old = own value (identity for masked lanes)
#define DPP_FMIN_STEP(v, CTRL) { \
        const int t_ = __builtin_amdgcn_update_dpp(__float_as_int(v), __float_as_int(v), (CTRL), 0xf, 0xf, false); \
        (v) = fminf((v), __int_as_float(t_)); \
    }
#define DPP_FMAX_STEP(v, CTRL) { \
        const int t_ = __builtin_amdgcn_update_dpp(__float_as_int(v), __float_as_int(v), (CTRL), 0xf, 0xf, false); \
        (v) = fmaxf((v), __int_as_float(t_)); \
    }
#define DPP_RED6(MACRO, v) \
        MACRO(v, 0x111) MACRO(v, 0x112) MACRO(v, 0x114) MACRO(v, 0x118) \
        MACRO(v, 0x142) MACRO(v, 0x143)

// ---------------------------------------------------------------------------
// One-time spatial ordering kernel: one block per cloud.
// keys: (quantized_x << 14) | orig_idx -> bitonic sort -> per-16-chunk
// re-sort by orig -> emit reordered coords + slot-major u16 map [16][1024].
// fps correctness does NOT depend on sort quality (map is a permutation);
// sort quality only affects pruning rate.
// ---------------------------------------------------------------------------
__global__ __launch_bounds__(SORT_THREADS)
void sort_kernel(const float* __restrict__ pos, float* __restrict__ pos_s,
                 u16* __restrict__ mapT)
{
    __shared__ u32 keys[PTS];          // 64 KiB
    const int cloud = blockIdx.x;
    const int tid   = threadIdx.x;
    const int ln    = tid & 63;
    const size_t b3 = (size_t)cloud * PTS * 3;

    // ---- x range of this cloud ----
    float mn = 1e30f, mx = -1e30f;
    for (int s = 0; s < PTS / SORT_THREADS; ++s) {
        const float x = pos[b3 + (size_t)(tid + s * SORT_THREADS) * 3];
        mn = fminf(mn, x);
        mx = fmaxf(mx, x);
    }
    DPP_RED6(DPP_FMIN_STEP, mn)
    DPP_RED6(DPP_FMAX_STEP, mx)
    float* red = (float*)keys;         // reuse LDS before keys are written
    const int nw = SORT_THREADS / 64;
    if (ln == 63) { red[tid >> 6] = mn; red[nw + (tid >> 6)] = mx; }
    __syncthreads();
    float xmin = red[0], xmax = red[nw];
    for (int w = 1; w < nw; ++w) {
        xmin = fminf(xmin, red[w]);
        xmax = fmaxf(xmax, red[nw + w]);
    }
    __syncthreads();

    // ---- build keys: 18-bit quantized x | 14-bit orig index ----
    const float scale = 262143.0f / fmaxf(xmax - xmin, 1e-30f);
    for (int s = 0; s < PTS / SORT_THREADS; ++s) {
        const int i = tid + s * SORT_THREADS;
        const float x = pos[b3 + (size_t)i * 3];
        const u32 q = (u32)fminf(fmaxf((x - xmin) * scale, 0.0f), 262143.0f);
        keys[i] = (q << 14) | (u32)i;
    }

    // ---- bitonic sort 16384 u32 keys in LDS ----
    for (u32 k = 2; k <= (u32)PTS; k <<= 1) {
        for (u32 j = k >> 1; j; j >>= 1) {
            __syncthreads();
            for (int s = 0; s < PTS / SORT_THREADS; ++s) {
                const u32 i = (u32)(tid + s * SORT_THREADS);
                const u32 p = i ^ j;
                if (p > i) {
                    const u32 a = keys[i], b = keys[p];
                    if (((i & k) == 0) == (a > b)) { keys[i] = b; keys[p] = a; }
                }
            }
        }
    }
    __syncthreads();

    // ---- within each 16-chunk (one fps thread's slots), re-sort ascending
    //      by ORIGINAL index -> exact first-occurrence tie semantics ----
    for (int c = 0; c < 2; ++c) {
        u32 loc[PPT];
        const int cb = tid * 32 + c * PPT;
        for (int s = 0; s < PPT; ++s) loc[s] = keys[cb + s] & (u32)(PTS - 1);
        for (int a = 1; a < PPT; ++a) {
            const u32 v = loc[a];
            int b = a;
            while (b > 0 && loc[b - 1] > v) { loc[b] = loc[b - 1]; --b; }
            loc[b] = v;
        }
        for (int s = 0; s < PPT; ++s) keys[cb + s] = loc[s];
    }
    __syncthreads();

    // ---- emit reordered coords (bit-copies) + slot-major map [16][1024] ----
    for (int s = 0; s < PTS / SORT_THREADS; ++s) {
        const int i = tid + s * SORT_THREADS;   // sorted position
        const u32 orig = keys[i];
        mapT[(size_t)cloud * PTS + (size_t)(i & (PPT - 1)) * FPS_THREADS + (i >> 4)] = (u16)orig;
        const size_t so = b3 + (size_t)i * 3;
        const size_t oo = b3 + (size_t)orig * 3;
        pos_s[so + 0] = pos[oo + 0];
        pos_s[so + 1] = pos[oo + 1];
        pos_s[so + 2] = pos[oo + 2];
    }
}

// ---------------------------------------------------------------------------
// Main FPS kernel (one block per cloud, 16 waves). SORTED=false fallback.
// ---------------------------------------------------------------------------
template<bool SORTED>
__global__ __launch_bounds__(FPS_THREADS)
__attribute__((amdgpu_waves_per_eu(4, 4)))
void fps_kernel(const float* __restrict__ pos,      // original (winner fetch, q0)
                const float* __restrict__ psrc,     // sorted coords (or == pos)
                const u16* __restrict__ mapT,       // slot-major orig map (or null)
                int* __restrict__ out)
{
#pragma clang fp contract(off)
    const int cloud = blockIdx.x;
    const int tid   = threadIdx.x;
    const int base  = cloud * PTS;
    const int wave  = tid >> 6;
    const int lane  = tid & 63;

    __shared__ u64 skey[2][NWAVES];
    __shared__ __attribute__((aligned(16))) u16 mlds[PTS];   // [slot][thread]

    if constexpr (SORTED) {
        // stage orig-index map into LDS (coalesced uint4 copy)
        const uint4* src = (const uint4*)(mapT + (size_t)cloud * PTS);
        uint4* dst = (uint4*)mlds;
#pragma unroll
        for (int s = 0; s < PTS * 2 / 16 / FPS_THREADS; ++s)   // 2 iters
            dst[s * FPS_THREADS + tid] = src[s * FPS_THREADS + tid];
        __syncthreads();
    }

    // ---- query = point 0 of cloud (ORIGINAL order) ----
    const float q0x = pos[(size_t)base * 3 + 0];
    const float q0y = pos[(size_t)base * 3 + 1];
    const float q0z = pos[(size_t)base * 3 + 2];
    v2f qx2 = {q0x, q0x}, qy2 = {q0y, q0y}, qz2 = {q0z, q0z};

    // ---- one-time vectorized load: 16 consecutive pts = 12 float4,
    //      loaded per-quad (3 float4 -> 6 v2f) to cap VGPR pressure ----
    const float4* pos4 = (const float4*)psrc;
    const int fo = cloud * (PTS * 3 / 4) + tid * (PPT * 3 / 4);   // 12 f4/thread

#define DECL(j) v2f XX##j, YY##j, ZZ##j, DD##j;
    PAIRS8_X(DECL)
#undef DECL

#define QUADLOAD(q, j0, j1) { \
        const float4 fa = pos4[fo + 3*(q) + 0]; \
        const float4 fb = pos4[fo + 3*(q) + 1]; \
        const float4 fc = pos4[fo + 3*(q) + 2]; \
        XX##j0 = (v2f){fa.x, fa.w}; \
        YY##j0 = (v2f){fa.y, fb.x}; \
        ZZ##j0 = (v2f){fa.z, fb.y}; \
        XX##j1 = (v2f){fb.z, fc.y}; \
        YY##j1 = (v2f){fb.w, fc.z}; \
        ZZ##j1 = (v2f){fc.x, fc.w}; }
    QUADLOAD(0, 0, 1) QUADLOAD(1, 2, 3) QUADLOAD(2, 4, 5) QUADLOAD(3, 6, 7)
#undef QUADLOAD

    // ---- pin coords in VGPRs: opaque defs => no remat, no reload ----
#define PIN8(a,b,c,d,e,g,h,k) asm volatile("" : "+v"(a),"+v"(b),"+v"(c),"+v"(d),"+v"(e),"+v"(g),"+v"(h),"+v"(k));
    PIN8(XX0, XX1, XX2, XX3, XX4, XX5, XX6, XX7)
    PIN8(YY0, YY1, YY2, YY3, YY4, YY5, YY6, YY7)
    PIN8(ZZ0, ZZ1, ZZ2, ZZ3, ZZ4, ZZ5, ZZ6, ZZ7)
#undef PIN8

    // ---- wave x-slab bounds (TRUE min/max of this wave's points) ----
    float wxlo, wxhi;
    {
        float mn = fminf(XX0.x, XX0.y);
        float mx = fmaxf(XX0.x, XX0.y);
#define MINMAX(j) { mn = fminf(mn, fminf(XX##j.x, XX##j.y)); \
                    mx = fmaxf(mx, fmaxf(XX##j.x, XX##j.y)); }
        MINMAX(1) MINMAX(2) MINMAX(3) MINMAX(4) MINMAX(5) MINMAX(6) MINMAX(7)
#undef MINMAX
        DPP_RED6(DPP_FMIN_STEP, mn)
        DPP_RED6(DPP_FMAX_STEP, mx)
        wxlo = __int_as_float(__builtin_amdgcn_readlane(__float_as_int(mn), 63));
        wxhi = __int_as_float(__builtin_amdgcn_readlane(__float_as_int(mx), 63));
    }

    // ---- init dists to point 0 + lane-local argmax ----
    float bd = -1.0f;
    int   bk = 0;
#define INITP(j) { \
        v2f dx = XX##j - qx2; \
        v2f dy = YY##j - qy2; \
        v2f dz = ZZ##j - qz2; \
        v2f nd = (dx * dx + dy * dy) + dz * dz; \
        DD##j = nd; \
        if (nd.x > bd) { bd = nd.x; bk = 2*(j); } \
        if (nd.y > bd) { bd = nd.y; bk = 2*(j) + 1; } \
    }
    PAIRS8_X(INITP)
#undef INITP

    if (tid == 0) out[cloud * M] = base;   // first sample = point 0

    // ---- initial wave key (same as the loop's active path) ----
    u32 c_hi, c_lo;                        // cached wave key (uniform)
    {
        int bi;
        if constexpr (SORTED) bi = (int)mlds[(bk << 10) + tid];
        else                  bi = tid * PPT + bk;
        u64 key = ((u64)__float_as_uint(bd) << 32) | (u32)(~bi);
        DPP_MAX_STEP(key, 0x111)
        DPP_MAX_STEP(key, 0x112)
        DPP_MAX_STEP(key, 0x114)
        DPP_MAX_STEP(key, 0x118)
        DPP_MAX_STEP(key, 0x142)
        DPP_MAX_STEP(key, 0x143)
        c_hi = (u32)__builtin_amdgcn_readlane((int)(u32)(key >> 32), 63);
        c_lo = (u32)__builtin_amdgcn_readlane((int)(u32)key, 63);
    }

    for (int i = 1; i < M; ++i) {
        // ---- publish this wave's current best key (cached; always valid) ----
        if (lane == 0) skey[i & 1][wave] = ((u64)c_hi << 32) | c_lo;
        __syncthreads();

        // ---- cross-wave: lanes hold the 16 wave keys, 4 DPP steps, lane 15 ----
        u64 key2 = skey[i & 1][lane & 15];
        DPP_MAX_STEP(key2, 0x111)
        DPP_MAX_STEP(key2, 0x112)
        DPP_MAX_STEP(key2, 0x114)
        DPP_MAX_STEP(key2, 0x118)   // lane 15 = max of keys 0..15
        const u32 wlo = (u32)__builtin_amdgcn_readlane((int)(u32)key2, 15);
        const int wi  = (int)(~wlo);            // winner ORIGINAL local index

        if (tid == 0) out[cloud * M + i] = base + wi;

        // ---- fetch winner coords from ORIGINAL array (uniform -> s_load) ----
        const float* qp = pos + (size_t)(base + wi) * 3;
        const float qx = qp[0], qy = qp[1], qz = qp[2];

        // ---- wave-level exact prune: skip iff dist_x(q, slab)^2 provably
        //      exceeds this wave's max min-dist (cached key hi) ----
        const float dlo  = wxlo - qx;
        const float dhi  = qx - wxhi;
        const float dgap = fmaxf(fmaxf(dlo, dhi), 0.0f);
        const float lb   = (dgap * dgap) * 0.9999f;   // margin >> fp32 error
        if (!(lb > __uint_as_float(c_hi))) {
            // ---- active: fused distance update + lane-local argmax ----
            qx2 = (v2f){qx, qx}; qy2 = (v2f){qy, qy}; qz2 = (v2f){qz, qz};
            bd = -1.0f; bk = 0;
#define UPD(j) { \
        v2f dx = XX##j - qx2; \
        v2f dy = YY##j - qy2; \
        v2f dz = ZZ##j - qz2; \
        v2f nd = (dx * dx + dy * dy) + dz * dz; \
        DD##j.x = fminf(DD##j.x, nd.x); \
        DD##j.y = fminf(DD##j.y, nd.y); \
        if (DD##j.x > bd) { bd = DD##j.x; bk = 2*(j); } \
        if (DD##j.y > bd) { bd = DD##j.y; bk = 2*(j) + 1; } \
    }
            PAIRS8_X(UPD)
#undef UPD
            int bi;
            if constexpr (SORTED) bi = (int)mlds[(bk << 10) + tid];
            else                  bi = tid * PPT + bk;
            u64 key = ((u64)__float_as_uint(bd) << 32) | (u32)(~bi);
            DPP_MAX_STEP(key, 0x111)
            DPP_MAX_STEP(key, 0x112)
            DPP_MAX_STEP(key, 0x114)
            DPP_MAX_STEP(key, 0x118)
            DPP_MAX_STEP(key, 0x142)
            DPP_MAX_STEP(key, 0x143)
            c_hi = (u32)__builtin_amdgcn_readlane((int)(u32)(key >> 32), 63);
            c_lo = (u32)__builtin_amdgcn_readlane((int)(u32)key, 63);
        }
        // skipped: DD/bd/bk/c_* unchanged -- provably identical to full update
    }
}

extern "C" void kernel_launch(void* const* d_in, const int* in_sizes, int n_in,
                              void* d_out, int out_size, void* d_ws, size_t ws_size,
                              hipStream_t stream) {
    const float* pos = (const float*)d_in[0];
    int* out = (int*)d_out;

    const size_t pos_s_bytes = (size_t)N_CLOUDS * PTS * 3 * sizeof(float);   // 3 MiB
    const size_t map_bytes   = (size_t)N_CLOUDS * PTS * sizeof(u16);         // 0.5 MiB
    if (d_ws && ws_size >= pos_s_bytes + map_bytes) {
        float* pos_s = (float*)d_ws;
        u16*   mapT  = (u16*)((char*)d_ws + pos_s_bytes);
        sort_kernel<<<N_CLOUDS, SORT_THREADS, 0, stream>>>(pos, pos_s, mapT);
        fps_kernel<true><<<N_CLOUDS, FPS_THREADS, 0, stream>>>(pos, pos_s, mapT, out);
    } else {
        fps_kernel<false><<<N_CLOUDS, FPS_THREADS, 0, stream>>>(pos, pos, nullptr, out);
    }
}